// Round 10
// baseline (570.296 us; speedup 1.0000x reference)
//
#include <hip/hip_runtime.h>
#include <hip/hip_bf16.h>

// ---------------- problem constants ----------------
#define Bn   4
#define Lq   1024
#define Dm   768
#define Mm   48
#define NEe  24
#define Pp   552          // NE*(NE-1)
#define Ee   576          // P + NE (self loops)
#define Hh   12
#define BSz  64
#define Rr   97
#define Nn   2208         // B*P
#define NPAD 112          // Rr padded to 7*16
#define NEG_SLOPE 0.2f

typedef short bf16x8 __attribute__((ext_vector_type(8)));
typedef float f32x4  __attribute__((ext_vector_type(4)));

static __device__ __forceinline__ ushort f2b(float x) {
    __hip_bfloat16 h = __float2bfloat16(x);
    return *reinterpret_cast<ushort*>(&h);
}
static __device__ __forceinline__ float b2f(ushort h) {
    uint u = ((uint)h) << 16;
    return __uint_as_float(u);
}
// split f32 into hi+lo bf16 (a ~= hi + lo, residual ~2^-18 rel)
static __device__ __forceinline__ void split2(float x, ushort& h, ushort& l) {
    h = f2b(x);
    l = f2b(x - b2f(h));
}

// ============================================================
__global__ void k_entity(const float* __restrict__ ctx, const int* __restrict__ mmap,
                         const float* __restrict__ emap, float* __restrict__ entity,
                         ushort* __restrict__ entH, ushort* __restrict__ entL)
{
    int x = blockIdx.x;              // b*NE + n
    int b = x / NEe;
    int rows[8]; float wts[8]; int nnz = 0;
    for (int m = 0; m < Mm; ++m) {
        float w = emap[(long)x * Mm + m];
        if (w != 0.f && nnz < 8) { rows[nnz] = mmap[b * Mm + m]; wts[nnz] = w; ++nnz; }
    }
    const float* cbase = ctx + (long)b * Lq * Dm;
    for (int d = threadIdx.x; d < Dm; d += 256) {
        float s = 0.f;
        for (int z = 0; z < nnz; ++z) s += wts[z] * expf(cbase[(long)rows[z] * Dm + d]);
        float v = logf(s);
        entity[(long)x * Dm + d] = v;
        ushort hh, ll; split2(v, hh, ll);
        entH[(long)x * Dm + d] = hh;
        entL[(long)x * Dm + d] = ll;
    }
}

__global__ void k_cur(const float* __restrict__ att, const int* __restrict__ mmap,
                      const float* __restrict__ emap, float* __restrict__ cur)
{
    int x = blockIdx.x;
    int b = x / (Hh * NEe); int rem = x % (Hh * NEe);
    int h = rem / NEe;      int n = rem % NEe;
    float cnt = 0.f;
    int rows[8]; float wts[8]; int nnz = 0;
    for (int m = 0; m < Mm; ++m) {
        float w = emap[((long)b * NEe + n) * Mm + m];
        cnt += w;
        if (w != 0.f && nnz < 8) { rows[nnz] = mmap[b * Mm + m]; wts[nnz] = w; ++nnz; }
    }
    float inv = 1.f / (cnt + 1e-20f);
    const float* abase = att + ((long)b * Hh + h) * (long)Lq * Lq;
    float* obase = cur + (long)x * Lq;
    for (int l = threadIdx.x; l < Lq; l += 256) {
        float s = 0.f;
        for (int z = 0; z < nnz; ++z) s += wts[z] * abase[(long)rows[z] * Lq + l];
        obase[l] = s * inv;
    }
}

// ca -> split hi/lo bf16
__global__ void k_ca(const float* __restrict__ cur, const int* __restrict__ hts,
                     ushort* __restrict__ caH, ushort* __restrict__ caL)
{
    int bp = blockIdx.x; int b = bp / Pp, p = bp % Pp;
    int n0 = hts[p], n1 = hts[Pp + p];
    __shared__ float red[256];
    float vals[4]; float lsum = 0.f;
    for (int t = 0; t < 4; ++t) {
        int l = threadIdx.x + t * 256;
        float v = 0.f;
        #pragma unroll
        for (int h = 0; h < Hh; ++h) {
            v += cur[(((long)b * Hh + h) * NEe + n0) * Lq + l] *
                 cur[(((long)b * Hh + h) * NEe + n1) * Lq + l];
        }
        vals[t] = v; lsum += v;
    }
    red[threadIdx.x] = lsum; __syncthreads();
    for (int s = 128; s > 0; s >>= 1) {
        if (threadIdx.x < s) red[threadIdx.x] += red[threadIdx.x + s];
        __syncthreads();
    }
    float inv = 1.f / (red[0] + 1e-20f);
    for (int t = 0; t < 4; ++t) {
        int l = threadIdx.x + t * 256;
        float v = vals[t] * inv;
        long idx = (long)bp * Lq + l;
        ushort hh, ll; split2(v, hh, ll);
        caH[idx] = hh; caL[idx] = ll;
    }
}

// ============================================================
// split-bf16 (3-MFMA) GEMM with IN-KERNEL split (tiny T-step only)
__global__ __launch_bounds__(256)
void k_gemm_split(const float* __restrict__ A, const float* __restrict__ W,
                  const float* __restrict__ bias, float* __restrict__ C,
                  int M, int N, int K, int lda, int ldw, int ldc,
                  long sA, long sW, long sC, int act)
{
    A += (long)blockIdx.z * sA;
    W += (long)blockIdx.z * sW;
    C += (long)blockIdx.z * sC;
    __shared__ ushort Ah[64][40], Al[64][40], Bh[64][40], Bl[64][40];
    const int tid = threadIdx.x;
    const int r0 = blockIdx.y * 64, c0 = blockIdx.x * 64;
    const int w = tid >> 6, l = tid & 63, lr = l & 15, lk = l >> 4;
    const int wr = (w >> 1) * 32, wc = (w & 1) * 32;
    f32x4 acc[2][2];
    #pragma unroll
    for (int m = 0; m < 2; ++m)
        #pragma unroll
        for (int n = 0; n < 2; ++n) acc[m][n] = (f32x4){0.f, 0.f, 0.f, 0.f};

    const int ar  = tid >> 3;
    const int kq  = (tid & 7) * 4;
    const int bkk = tid >> 4;
    const int cc4 = (tid & 15) * 4;
    const float4 z4 = make_float4(0.f, 0.f, 0.f, 0.f);

    for (int k0 = 0; k0 < K; k0 += 32) {
        #pragma unroll
        for (int s = 0; s < 2; ++s) {
            int r = ar + s * 32;
            int gr = r0 + r;
            float4 v = (gr < M) ? *(const float4*)&A[(long)gr * lda + k0 + kq] : z4;
            ushort h0, l0, h1, l1;
            split2(v.x, h0, l0); split2(v.y, h1, l1);
            *(uint*)&Ah[r][kq]     = (uint)h0 | ((uint)h1 << 16);
            *(uint*)&Al[r][kq]     = (uint)l0 | ((uint)l1 << 16);
            split2(v.z, h0, l0); split2(v.w, h1, l1);
            *(uint*)&Ah[r][kq + 2] = (uint)h0 | ((uint)h1 << 16);
            *(uint*)&Al[r][kq + 2] = (uint)l0 | ((uint)l1 << 16);
        }
        #pragma unroll
        for (int s = 0; s < 2; ++s) {
            int kk = bkk + s * 16;
            float4 v = *(const float4*)&W[(long)(k0 + kk) * ldw + c0 + cc4];
            ushort hh, ll;
            split2(v.x, hh, ll); Bh[cc4 + 0][kk] = hh; Bl[cc4 + 0][kk] = ll;
            split2(v.y, hh, ll); Bh[cc4 + 1][kk] = hh; Bl[cc4 + 1][kk] = ll;
            split2(v.z, hh, ll); Bh[cc4 + 2][kk] = hh; Bl[cc4 + 2][kk] = ll;
            split2(v.w, hh, ll); Bh[cc4 + 3][kk] = hh; Bl[cc4 + 3][kk] = ll;
        }
        __syncthreads();
        bf16x8 fah[2], fal[2], fbh[2], fbl[2];
        #pragma unroll
        for (int m = 0; m < 2; ++m) {
            fah[m] = *(const bf16x8*)&Ah[wr + m * 16 + lr][lk * 8];
            fal[m] = *(const bf16x8*)&Al[wr + m * 16 + lr][lk * 8];
        }
        #pragma unroll
        for (int n = 0; n < 2; ++n) {
            fbh[n] = *(const bf16x8*)&Bh[wc + n * 16 + lr][lk * 8];
            fbl[n] = *(const bf16x8*)&Bl[wc + n * 16 + lr][lk * 8];
        }
        #pragma unroll
        for (int m = 0; m < 2; ++m)
            #pragma unroll
            for (int n = 0; n < 2; ++n) {
                acc[m][n] = __builtin_amdgcn_mfma_f32_16x16x32_bf16(fal[m], fbh[n], acc[m][n], 0, 0, 0);
                acc[m][n] = __builtin_amdgcn_mfma_f32_16x16x32_bf16(fah[m], fbl[n], acc[m][n], 0, 0, 0);
                acc[m][n] = __builtin_amdgcn_mfma_f32_16x16x32_bf16(fah[m], fbh[n], acc[m][n], 0, 0, 0);
            }
        __syncthreads();
    }
    #pragma unroll
    for (int m = 0; m < 2; ++m) {
        #pragma unroll
        for (int q = 0; q < 4; ++q) {
            int gr = r0 + wr + m * 16 + lk * 4 + q;
            if (gr >= M) continue;
            #pragma unroll
            for (int n = 0; n < 2; ++n) {
                int gc = c0 + wc + n * 16 + lr;
                float v = acc[m][n][q] + (bias ? bias[gc] : 0.f);
                if (act) v = tanhf(v);
                C[(long)gr * ldc + gc] = v;
            }
        }
    }
}

// ============================================================
// 64^2-tile pre-split 3-MFMA GEMM (batched): C = act(A @ Bt^T + bias)
__global__ __launch_bounds__(256)
void k_gemm3_64(const ushort* __restrict__ AH, const ushort* __restrict__ AL,
                const ushort* __restrict__ BH, const ushort* __restrict__ BL,
                const float* __restrict__ bias, float* __restrict__ C,
                ushort* __restrict__ Ch, ushort* __restrict__ Cl,
                int M, int N, int K, int ldc, int act,
                long sA, long sB, long sC)
{
    AH += blockIdx.z * sA; AL += blockIdx.z * sA;
    BH += blockIdx.z * sB; BL += blockIdx.z * sB;
    C  += blockIdx.z * sC;
    ushort* ChB = Ch ? Ch + blockIdx.z * sC : (ushort*)nullptr;
    ushort* ClB = Cl ? Cl + blockIdx.z * sC : (ushort*)nullptr;
    __shared__ ushort AsH[64][40], AsL[64][40], BsH[64][40], BsL[64][40];
    const int tid = threadIdx.x;
    const int r0 = blockIdx.y * 64, c0 = blockIdx.x * 64;
    const int w = tid >> 6, l = tid & 63, lr = l & 15, lk = l >> 4;
    const int wr = (w >> 1) * 32, wc = (w & 1) * 32;
    f32x4 acc[2][2];
    #pragma unroll
    for (int m = 0; m < 2; ++m)
        #pragma unroll
        for (int n = 0; n < 2; ++n) acc[m][n] = (f32x4){0.f, 0.f, 0.f, 0.f};

    const int srow = tid >> 2, scb = (tid & 1) * 16;
    const bool doB = (tid >> 1) & 1;
    const bool ok = doB ? (c0 + srow < N) : (r0 + srow < M);
    const long g = doB ? (long)(c0 + srow) : (long)(r0 + srow);
    const ushort* pH = (doB ? BH : AH) + (ok ? g : 0) * (long)K;
    const ushort* pL = (doB ? BL : AL) + (ok ? g : 0) * (long)K;
    ushort (*dH)[40] = doB ? BsH : AsH;
    ushort (*dL)[40] = doB ? BsL : AsL;
    const uint4 z4 = make_uint4(0, 0, 0, 0);
    for (int k0 = 0; k0 < K; k0 += 32) {
        int kc = k0 + scb;
        *(uint4*)&dH[srow][scb]     = ok ? *(const uint4*)&pH[kc]     : z4;
        *(uint4*)&dH[srow][scb + 8] = ok ? *(const uint4*)&pH[kc + 8] : z4;
        *(uint4*)&dL[srow][scb]     = ok ? *(const uint4*)&pL[kc]     : z4;
        *(uint4*)&dL[srow][scb + 8] = ok ? *(const uint4*)&pL[kc + 8] : z4;
        __syncthreads();
        bf16x8 ah[2], al_[2], bh[2], bl_[2];
        #pragma unroll
        for (int m = 0; m < 2; ++m) {
            ah[m]  = *(const bf16x8*)&AsH[wr + m * 16 + lr][lk * 8];
            al_[m] = *(const bf16x8*)&AsL[wr + m * 16 + lr][lk * 8];
        }
        #pragma unroll
        for (int n = 0; n < 2; ++n) {
            bh[n]  = *(const bf16x8*)&BsH[wc + n * 16 + lr][lk * 8];
            bl_[n] = *(const bf16x8*)&BsL[wc + n * 16 + lr][lk * 8];
        }
        #pragma unroll
        for (int m = 0; m < 2; ++m)
            #pragma unroll
            for (int n = 0; n < 2; ++n) {
                acc[m][n] = __builtin_amdgcn_mfma_f32_16x16x32_bf16(al_[m], bh[n], acc[m][n], 0, 0, 0);
                acc[m][n] = __builtin_amdgcn_mfma_f32_16x16x32_bf16(ah[m], bl_[n], acc[m][n], 0, 0, 0);
                acc[m][n] = __builtin_amdgcn_mfma_f32_16x16x32_bf16(ah[m], bh[n], acc[m][n], 0, 0, 0);
            }
        __syncthreads();
    }
    #pragma unroll
    for (int m = 0; m < 2; ++m) {
        #pragma unroll
        for (int q = 0; q < 4; ++q) {
            int gr = r0 + wr + m * 16 + lk * 4 + q;
            if (gr >= M) continue;
            #pragma unroll
            for (int n = 0; n < 2; ++n) {
                int gc = c0 + wc + n * 16 + lr;
                float v = acc[m][n][q] + (bias ? bias[gc] : 0.f);
                if (act) v = tanhf(v);
                long oi = (long)gr * ldc + gc;
                C[oi] = v;
                if (ChB) { ushort hh, ll; split2(v, hh, ll); ChB[oi] = hh; ClB[oi] = ll; }
            }
        }
    }
}

// 64^2-tile pre-split 3-MFMA GEMM, gathered concat, tanh; z picks (sel,W,bias,C)
__global__ __launch_bounds__(256)
void k_gemm3_cat64(const ushort* __restrict__ ndH, const ushort* __restrict__ ndL,
                   const ushort* __restrict__ ftH, const ushort* __restrict__ ftL,
                   const int* __restrict__ hts,
                   const ushort* __restrict__ BH0, const ushort* __restrict__ BL0,
                   const ushort* __restrict__ BH1, const ushort* __restrict__ BL1,
                   const float* __restrict__ bias0, const float* __restrict__ bias1,
                   float* __restrict__ C0, float* __restrict__ C1)
{
    const int zz = blockIdx.z;
    const int* sel = hts + (zz ? Pp : 0);
    const ushort* BH = zz ? BH1 : BH0;
    const ushort* BL = zz ? BL1 : BL0;
    const float* bias = zz ? bias1 : bias0;
    float* C = zz ? C1 : C0;
    __shared__ ushort AsH[64][40], AsL[64][40], BsH[64][40], BsL[64][40];
    const int tid = threadIdx.x;
    const int r0 = blockIdx.y * 64, c0 = blockIdx.x * 64;
    const int w = tid >> 6, l = tid & 63, lr = l & 15, lk = l >> 4;
    const int wr = (w >> 1) * 32, wc = (w & 1) * 32;
    f32x4 acc[2][2];
    #pragma unroll
    for (int m = 0; m < 2; ++m)
        #pragma unroll
        for (int n = 0; n < 2; ++n) acc[m][n] = (f32x4){0.f, 0.f, 0.f, 0.f};

    const int srow = tid >> 2, scb = (tid & 1) * 16;
    const bool doB = (tid >> 1) & 1;
    const ushort *pH0, *pL0, *pH1, *pL1;
    bool ok;
    if (doB) {
        long gc = c0 + srow;            // N=768 exact
        ok = true;
        pH0 = BH + gc * (long)(2 * Dm); pL0 = BL + gc * (long)(2 * Dm);
        pH1 = pH0; pL1 = pL0;
    } else {
        int gra = r0 + srow;
        ok = gra < Nn;
        int grc = ok ? gra : Nn - 1;
        int b = grc / Pp, p = grc % Pp;
        pH0 = ndH + ((long)b * NEe + sel[p]) * Dm;
        pL0 = ndL + ((long)b * NEe + sel[p]) * Dm;
        pH1 = ftH + (long)grc * Dm - Dm;
        pL1 = ftL + (long)grc * Dm - Dm;
    }
    ushort (*dH)[40] = doB ? BsH : AsH;
    ushort (*dL)[40] = doB ? BsL : AsL;
    const uint4 z4 = make_uint4(0, 0, 0, 0);
    for (int k0 = 0; k0 < 2 * Dm; k0 += 32) {
        const ushort* sH = ((k0 < Dm) ? pH0 : pH1) + k0 + scb;
        const ushort* sL = ((k0 < Dm) ? pL0 : pL1) + k0 + scb;
        *(uint4*)&dH[srow][scb]     = ok ? *(const uint4*)sH       : z4;
        *(uint4*)&dH[srow][scb + 8] = ok ? *(const uint4*)(sH + 8) : z4;
        *(uint4*)&dL[srow][scb]     = ok ? *(const uint4*)sL       : z4;
        *(uint4*)&dL[srow][scb + 8] = ok ? *(const uint4*)(sL + 8) : z4;
        __syncthreads();
        bf16x8 ah[2], al_[2], bh[2], bl_[2];
        #pragma unroll
        for (int m = 0; m < 2; ++m) {
            ah[m]  = *(const bf16x8*)&AsH[wr + m * 16 + lr][lk * 8];
            al_[m] = *(const bf16x8*)&AsL[wr + m * 16 + lr][lk * 8];
        }
        #pragma unroll
        for (int n = 0; n < 2; ++n) {
            bh[n]  = *(const bf16x8*)&BsH[wc + n * 16 + lr][lk * 8];
            bl_[n] = *(const bf16x8*)&BsL[wc + n * 16 + lr][lk * 8];
        }
        #pragma unroll
        for (int m = 0; m < 2; ++m)
            #pragma unroll
            for (int n = 0; n < 2; ++n) {
                acc[m][n] = __builtin_amdgcn_mfma_f32_16x16x32_bf16(al_[m], bh[n], acc[m][n], 0, 0, 0);
                acc[m][n] = __builtin_amdgcn_mfma_f32_16x16x32_bf16(ah[m], bl_[n], acc[m][n], 0, 0, 0);
                acc[m][n] = __builtin_amdgcn_mfma_f32_16x16x32_bf16(ah[m], bh[n], acc[m][n], 0, 0, 0);
            }
        __syncthreads();
    }
    #pragma unroll
    for (int m = 0; m < 2; ++m) {
        #pragma unroll
        for (int q = 0; q < 4; ++q) {
            int gr = r0 + wr + m * 16 + lk * 4 + q;
            if (gr >= Nn) continue;
            #pragma unroll
            for (int n = 0; n < 2; ++n) {
                int gc = c0 + wc + n * 16 + lr;
                C[(long)gr * Dm + gc] = tanhf(acc[m][n][q] + bias[gc]);
            }
        }
    }
}

// 64^2-tile plain bf16 GEMM: C = A @ Bt^T
__global__ __launch_bounds__(256)
void k_gemm_bf64(const ushort* __restrict__ A, const ushort* __restrict__ Bt,
                 float* __restrict__ C, int M, int N, int K, int ldc)
{
    __shared__ ushort As[64][40], Bs[64][40];
    const int tid = threadIdx.x;
    const int r0 = blockIdx.y * 64, c0 = blockIdx.x * 64;
    const int w = tid >> 6, l = tid & 63, lr = l & 15, lk = l >> 4;
    const int wr = (w >> 1) * 32, wc = (w & 1) * 32;
    f32x4 acc[2][2];
    #pragma unroll
    for (int m = 0; m < 2; ++m)
        #pragma unroll
        for (int n = 0; n < 2; ++n) acc[m][n] = (f32x4){0.f, 0.f, 0.f, 0.f};

    const int srow = tid >> 2, scb = (tid & 1) * 16;
    const bool doB = (tid >> 1) & 1;
    const bool ok = doB ? (c0 + srow < N) : (r0 + srow < M);
    const long g = doB ? (long)(c0 + srow) : (long)(r0 + srow);
    const ushort* p = (doB ? Bt : A) + (ok ? g : 0) * (long)K;
    ushort (*d)[40] = doB ? Bs : As;
    const uint4 z4 = make_uint4(0, 0, 0, 0);
    for (int k0 = 0; k0 < K; k0 += 32) {
        int kc = k0 + scb;
        *(uint4*)&d[srow][scb]     = ok ? *(const uint4*)&p[kc]     : z4;
        *(uint4*)&d[srow][scb + 8] = ok ? *(const uint4*)&p[kc + 8] : z4;
        __syncthreads();
        bf16x8 af[2], bf_[2];
        #pragma unroll
        for (int m = 0; m < 2; ++m) af[m]  = *(const bf16x8*)&As[wr + m * 16 + lr][lk * 8];
        #pragma unroll
        for (int n = 0; n < 2; ++n) bf_[n] = *(const bf16x8*)&Bs[wc + n * 16 + lr][lk * 8];
        #pragma unroll
        for (int m = 0; m < 2; ++m)
            #pragma unroll
            for (int n = 0; n < 2; ++n)
                acc[m][n] = __builtin_amdgcn_mfma_f32_16x16x32_bf16(af[m], bf_[n], acc[m][n], 0, 0, 0);
        __syncthreads();
    }
    #pragma unroll
    for (int m = 0; m < 2; ++m) {
        #pragma unroll
        for (int q = 0; q < 4; ++q) {
            int gr = r0 + wr + m * 16 + lk * 4 + q;
            if (gr >= M) continue;
            #pragma unroll
            for (int n = 0; n < 2; ++n) {
                int gc = c0 + wc + n * 16 + lr;
                C[(long)gr * ldc + gc] = acc[m][n][q];
            }
        }
    }
}

// 64^2-tile plain bf16 GEMM, gathered concat, tanh; z picks (sel,W,bias,C)
__global__ __launch_bounds__(256)
void k_gemm_bf_cat64(const ushort* __restrict__ nodes, const ushort* __restrict__ feat,
                     const int* __restrict__ hts,
                     const ushort* __restrict__ Bt0, const ushort* __restrict__ Bt1,
                     const float* __restrict__ bias0, const float* __restrict__ bias1,
                     float* __restrict__ C0, float* __restrict__ C1)
{
    const int zz = blockIdx.z;
    const int* sel = hts + (zz ? Pp : 0);
    const ushort* Bt = zz ? Bt1 : Bt0;
    const float* bias = zz ? bias1 : bias0;
    float* C = zz ? C1 : C0;
    __shared__ ushort As[64][40], Bs[64][40];
    const int tid = threadIdx.x;
    const int r0 = blockIdx.y * 64, c0 = blockIdx.x * 64;
    const int w = tid >> 6, l = tid & 63, lr = l & 15, lk = l >> 4;
    const int wr = (w >> 1) * 32, wc = (w & 1) * 32;
    f32x4 acc[2][2];
    #pragma unroll
    for (int m = 0; m < 2; ++m)
        #pragma unroll
        for (int n = 0; n < 2; ++n) acc[m][n] = (f32x4){0.f, 0.f, 0.f, 0.f};

    const int srow = tid >> 2, scb = (tid & 1) * 16;
    const bool doB = (tid >> 1) & 1;
    const ushort *p0, *p1;
    bool ok;
    if (doB) {
        long gc = c0 + srow;
        ok = true;
        p0 = Bt + gc * (long)(2 * Dm);
        p1 = p0;
    } else {
        int gra = r0 + srow;
        ok = gra < Nn;
        int grc = ok ? gra : Nn - 1;
        int b = grc / Pp, p = grc % Pp;
        p0 = nodes + ((long)b * NEe + sel[p]) * Dm;
        p1 = feat + (long)grc * Dm - Dm;
    }
    ushort (*d)[40] = doB ? Bs : As;
    const uint4 z4 = make_uint4(0, 0, 0, 0);
    for (int k0 = 0; k0 < 2 * Dm; k0 += 32) {
        const ushort* s = ((k0 < Dm) ? p0 : p1) + k0 + scb;
        *(uint4*)&d[srow][scb]     = ok ? *(const uint4*)s       : z4;
        *(uint4*)&d[srow][scb + 8] = ok ? *(const uint4*)(s + 8) : z4;
        __syncthreads();
        bf16x8 af[2], bf_[2];
        #pragma unroll
        for (int m = 0; m < 2; ++m) af[m]  = *(const bf16x8*)&As[wr + m * 16 + lr][lk * 8];
        #pragma unroll
        for (int n = 0; n < 2; ++n) bf_[n] = *(const bf16x8*)&Bs[wc + n * 16 + lr][lk * 8];
        #pragma unroll
        for (int m = 0; m < 2; ++m)
            #pragma unroll
            for (int n = 0; n < 2; ++n)
                acc[m][n] = __builtin_amdgcn_mfma_f32_16x16x32_bf16(af[m], bf_[n], acc[m][n], 0, 0, 0);
        __syncthreads();
    }
    #pragma unroll
    for (int m = 0; m < 2; ++m) {
        #pragma unroll
        for (int q = 0; q < 4; ++q) {
            int gr = r0 + wr + m * 16 + lk * 4 + q;
            if (gr >= Nn) continue;
            #pragma unroll
            for (int n = 0; n < 2; ++n) {
                int gc = c0 + wc + n * 16 + lr;
                C[(long)gr * Dm + gc] = tanhf(acc[m][n][q] + bias[gc]);
            }
        }
    }
}

// Wbin [(h*64+i)*64+j][2] -> Wb2[h][j][i*2+o] f32
__global__ void k_wbinT(const float* __restrict__ W, float* __restrict__ out)
{
    int h = blockIdx.x;              // 0..11
    for (int idx = threadIdx.x; idx < 64 * 128; idx += 256) {
        int j = idx >> 7, io = idx & 127;
        int i = io >> 1, o = io & 1;
        out[(long)h * 64 * 128 + idx] = W[(((long)h * 64 + i) * 64 + j) * 2 + o];
    }
}

// out0[n][o] = bbin[o] + sum_{h,i} act1[n][h*64+i] * T[h][n][i*2+o]; also mask
__global__ void k_binred(const float* __restrict__ act1, const float* __restrict__ T,
                         const float* __restrict__ bias, float* __restrict__ out0,
                         int* __restrict__ maskb)
{
    int w = threadIdx.x >> 6, l = threadIdx.x & 63;
    int n = blockIdx.x * 4 + w;
    if (n >= Nn) return;
    float a0 = 0.f, a1 = 0.f;
    #pragma unroll
    for (int h = 0; h < Hh; ++h) {
        float a = act1[(long)n * Dm + h * 64 + l];
        const float* t = T + ((long)(h * Nn + n)) * 128 + l * 2;
        a0 += a * t[0];
        a1 += a * t[1];
    }
    #pragma unroll
    for (int off = 32; off > 0; off >>= 1) {
        a0 += __shfl_down(a0, off);
        a1 += __shfl_down(a1, off);
    }
    if (l == 0) {
        float v0 = a0 + bias[0], v1 = a1 + bias[1];
        out0[n * 2 + 0] = v0;
        out0[n * 2 + 1] = v1;
        maskb[n] = v1 > v0 ? 1 : 0;
    }
}

// ---------- batched weight transpose kernels ----------
__global__ void k_wT4(const float* __restrict__ i0, const float* __restrict__ i1,
                      const float* __restrict__ i2, const float* __restrict__ i3,
                      ushort* __restrict__ o0, ushort* __restrict__ o1,
                      ushort* __restrict__ o2, ushort* __restrict__ o3)
{
    const float* in; ushort* out;
    switch (blockIdx.z) {
        case 0: in = i0; out = o0; break;
        case 1: in = i1; out = o1; break;
        case 2: in = i2; out = o2; break;
        default: in = i3; out = o3; break;
    }
    __shared__ float t[32][33];
    int k0 = blockIdx.y * 32, n0 = blockIdx.x * 32;
    int tx = threadIdx.x & 31, ty = threadIdx.x >> 5;
    #pragma unroll
    for (int s = 0; s < 4; ++s)
        t[ty + s * 8][tx] = in[(long)(k0 + ty + s * 8) * Dm + n0 + tx];
    __syncthreads();
    #pragma unroll
    for (int s = 0; s < 4; ++s)
        out[(long)(n0 + ty + s * 8) * Dm + k0 + tx] = f2b(t[tx][ty + s * 8]);
}

__global__ void k_wT2(const float* __restrict__ i0, const float* __restrict__ i1,
                      ushort* __restrict__ o0, ushort* __restrict__ o1, int K, int N)
{
    const float* in = blockIdx.z ? i1 : i0;
    ushort* out = blockIdx.z ? o1 : o0;
    __shared__ float t[32][33];
    int k0 = blockIdx.y * 32, n0 = blockIdx.x * 32;
    int tx = threadIdx.x & 31, ty = threadIdx.x >> 5;
    #pragma unroll
    for (int s = 0; s < 4; ++s)
        t[ty + s * 8][tx] = in[(long)(k0 + ty + s * 8) * N + n0 + tx];
    __syncthreads();
    #pragma unroll
    for (int s = 0; s < 4; ++s)
        out[(long)(n0 + ty + s * 8) * K + k0 + tx] = f2b(t[tx][ty + s * 8]);
}

__global__ void k_wT_split2(const float* __restrict__ i0, const float* __restrict__ i1,
                            ushort* __restrict__ oH0, ushort* __restrict__ oL0,
                            ushort* __restrict__ oH1, ushort* __restrict__ oL1,
                            int K, int N)
{
    const float* in = blockIdx.z ? i1 : i0;
    ushort* outH = blockIdx.z ? oH1 : oH0;
    ushort* outL = blockIdx.z ? oL1 : oL0;
    __shared__ float t[32][33];
    int k0 = blockIdx.y * 32, n0 = blockIdx.x * 32;
    int tx = threadIdx.x & 31, ty = threadIdx.x >> 5;
    #pragma unroll
    for (int s = 0; s < 4; ++s)
        t[ty + s * 8][tx] = in[(long)(k0 + ty + s * 8) * N + n0 + tx];
    __syncthreads();
    #pragma unroll
    for (int s = 0; s < 4; ++s) {
        float v = t[tx][ty + s * 8];
        ushort hh, ll; split2(v, hh, ll);
        long oi = (long)(n0 + ty + s * 8) * K + k0 + tx;
        outH[oi] = hh;
        outL[oi] = ll;
    }
}

__global__ void k_ctx_split(const float* __restrict__ ctx, ushort* __restrict__ outH,
                            ushort* __restrict__ outL)
{
    const float* in = ctx + (long)blockIdx.z * Lq * Dm;
    ushort* oH = outH + (long)blockIdx.z * Dm * Lq;
    ushort* oL = outL + (long)blockIdx.z * Dm * Lq;
    __shared__ float t[32][33];
    int k0 = blockIdx.y * 32, n0 = blockIdx.x * 32;   // k over Lq, n over Dm
    int tx = threadIdx.x & 31, ty = threadIdx.x >> 5;
    #pragma unroll
    for (int s = 0; s < 4; ++s)
        t[ty + s * 8][tx] = in[(long)(k0 + ty + s * 8) * Dm + n0 + tx];
    __syncthreads();
    #pragma unroll
    for (int s = 0; s < 4; ++s) {
        float v = t[tx][ty + s * 8];
        ushort hh, ll; split2(v, hh, ll);
        long oi = (long)(n0 + ty + s * 8) * Lq + k0 + tx;
        oH[oi] = hh;
        oL[oi] = ll;
    }
}

// Wrel [(h*64+i)*64+j][97] -> WrelB[(hi*112 + o)*64 + j] bf16 (o>=97 -> 0)
__global__ void k_wrelT(const float* __restrict__ W, ushort* __restrict__ out)
{
    int hi = blockIdx.x;            // 0..767
    for (int idx = threadIdx.x; idx < NPAD * 64; idx += 256) {
        int o = idx >> 6, j = idx & 63;
        float v = (o < Rr) ? W[((long)hi * 64 + j) * Rr + o] : 0.f;
        out[(long)hi * NPAD * 64 + idx] = f2b(v);
    }
}

// ---------- MFMA blockwise bilinear (relation head), j-split + XCD + W-prefetch ----------
__global__ __launch_bounds__(256)
void k_gbl_mfma(const float* __restrict__ Aact, const float* __restrict__ Cact,
                const ushort* __restrict__ Wt, float* __restrict__ part)
{
    const int bid = blockIdx.x;      // 0..431
    const int xcd = bid & 7, sb = bid >> 3;   // sb 0..53
    int h, t;
    if (sb < 36) { h = xcd;             t = sb; }
    else         { h = 8 + (xcd >> 1);  t = (sb - 36) + 18 * (xcd & 1); }
    const int rb = t >> 1, jh = t & 1;
    const int r0 = rb * 128;
    const int j0 = jh * 32;
    __shared__ float a_s[128][68];
    const int tid = threadIdx.x;
    {   // stage a-block [128][64]
        int row = tid >> 1, cb = (tid & 1) * 32;
        long gr = r0 + row;
        if (gr < Nn) {
            const float* ap = Aact + gr * Dm + h * BSz + cb;
            #pragma unroll
            for (int q = 0; q < 32; q += 4)
                *(float4*)&a_s[row][cb + q] = *(const float4*)&ap[q];
        } else {
            #pragma unroll
            for (int q = 0; q < 32; ++q) a_s[row][cb + q] = 0.f;
        }
    }
    __syncthreads();
    const int w = tid >> 6, l = tid & 63, lr = l & 15, lk = l >> 4;
    const int wr = w * 32;
    f32x4 acc[2][7];
    #pragma unroll
    for (int m = 0; m < 2; ++m)
        #pragma unroll
        for (int n = 0; n < 7; ++n) acc[m][n] = (f32x4){0.f, 0.f, 0.f, 0.f};

    const ushort* wbase = Wt + (long)h * 64 * NPAD * 64 + j0 + lk * 8;   // [i][o][j]
    float cc[2][8];
    #pragma unroll
    for (int m = 0; m < 2; ++m) {
        int crow = r0 + wr + m * 16 + lr;
        if (crow >= Nn) crow = Nn - 1;   // a=0 there anyway
        const float* cp = Cact + (long)crow * Dm + h * BSz + j0 + lk * 8;
        float4 clo = *(const float4*)cp;
        float4 chi = *(const float4*)(cp + 4);
        cc[m][0] = clo.x; cc[m][1] = clo.y; cc[m][2] = clo.z; cc[m][3] = clo.w;
        cc[m][4] = chi.x; cc[m][5] = chi.y; cc[m][6] = chi.z; cc[m][7] = chi.w;
    }
    // double-buffered W prefetch: load i+1's 7 fragments while computing i
    bf16x8 bfr[2][7];
    #pragma unroll
    for (int n = 0; n < 7; ++n)
        bfr[0][n] = *(const bf16x8*)(wbase + (long)(n * 16 + lr) * 64);
    for (int i = 0; i < 64; ++i) {
        const int cur = i & 1;
        if (i < 63) {
            const ushort* wp = wbase + (long)(i + 1) * NPAD * 64;
            #pragma unroll
            for (int n = 0; n < 7; ++n)
                bfr[cur ^ 1][n] = *(const bf16x8*)(wp + (long)(n * 16 + lr) * 64);
        }
        #pragma unroll
        for (int m = 0; m < 2; ++m) {
            float av = a_s[wr + m * 16 + lr][i];
            bf16x8 af;
            #pragma unroll
            for (int q = 0; q < 8; ++q)
                af[q] = (short)f2b(av * cc[m][q]);
            #pragma unroll
            for (int n = 0; n < 7; ++n)
                acc[m][n] = __builtin_amdgcn_mfma_f32_16x16x32_bf16(af, bfr[cur][n], acc[m][n], 0, 0, 0);
        }
    }
    float* pdst = part + ((long)(h * 2 + jh) * Nn) * NPAD;
    #pragma unroll
    for (int m = 0; m < 2; ++m) {
        #pragma unroll
        for (int q = 0; q < 4; ++q) {
            int gr = r0 + wr + m * 16 + lk * 4 + q;
            if (gr >= Nn) continue;
            #pragma unroll
            for (int n = 0; n < 7; ++n) {
                int o = n * 16 + lr;
                pdst[(long)gr * NPAD + o] = acc[m][n][q];
            }
        }
    }
}

__global__ void k_rel_reduce(const float* __restrict__ part, const float* __restrict__ bias,
                             float* __restrict__ out)
{
    int idx = blockIdx.x * 256 + threadIdx.x;
    if (idx >= Nn * Rr) return;
    int n = idx / Rr, o = idx % Rr;
    float s = bias[o];
    #pragma unroll
    for (int h = 0; h < 2 * Hh; ++h) s += part[((long)h * Nn + n) * NPAD + o];
    out[idx] = s;
}

// f_out assembly + fused edge score + fused new_ci (bf16)
__global__ void k_fassemble_score(const float* __restrict__ fij, const float* __restrict__ ni,
                                  const float* __restrict__ nj, const float* __restrict__ eb,
                                  const int* __restrict__ hts, float* __restrict__ fout, int ldn,
                                  const float* __restrict__ attp, const int* __restrict__ mask,
                                  float* __restrict__ score,
                                  const float* __restrict__ ci, ushort* __restrict__ newci)
{
    int be = blockIdx.x; int b = be / Ee, e = be % Ee;
    int sn, dn; const float* fe = nullptr;
    if (e < Pp) { sn = hts[e]; dn = hts[Pp + e]; fe = fij + ((long)b * Pp + e) * Dm; }
    else        { sn = dn = e - Pp; }
    const float* nib = ni + ((long)b * NEe + sn) * ldn;
    const float* njb = nj + ((long)b * NEe + dn) * ldn;
    float* ob = fout + (long)be * Dm;
    const bool okm = (e >= Pp) || (mask[b * Pp + e] != 0);
    const long nrow = (long)b * Pp + e;       // valid when e < Pp
    __shared__ float sd[Dm];
    for (int d = threadIdx.x; d < Dm; d += 256) {
        float v = (fe ? fe[d] : 0.f) + nib[d] + njb[d] + eb[d];
        ob[d] = v;
        float lr = v >= 0.f ? v : NEG_SLOPE * v;
        sd[d] = lr * attp[d];
        if (e < Pp)
            newci[nrow * Dm + d] = f2b(okm ? v : ci[nrow * Dm + d]);
    }
    __syncthreads();
    const int wv = threadIdx.x >> 6, ln = threadIdx.x & 63;
    for (int h = wv; h < Hh; h += 4) {
        float s = sd[h * 64 + ln];
        #pragma unroll
        for (int off = 32; off > 0; off >>= 1) s += __shfl_down(s, off);
        if (ln == 0) score[(long)be * Hh + h] = okm ? s : -1e30f;
    }
}

// merged edge-softmax + node aggregation; block = (b,n); attw in LDS
__global__ void k_egat_att(const float* __restrict__ score, const float* __restrict__ hsrcB,
                           ushort* __restrict__ nout, int ldn)
{
    int bnn = blockIdx.x; int b = bnn / NEe, n = bnn % NEe;
    __shared__ float aw[NEe][Hh + 1];
    int tid = threadIdx.x;
    if (tid < Hh) {
        int h = tid;
        float sc[NEe];
        float smax = -3e38f;
        #pragma unroll
        for (int hh = 0; hh < NEe; ++hh) {
            int e;
            if (hh == n) e = Pp + n;
            else         e = hh * (NEe - 1) + (n - (n > hh ? 1 : 0));
            float v = score[((long)b * Ee + e) * Hh + h];
            sc[hh] = v;
            smax = fmaxf(smax, v);
        }
        float den = 0.f;
        #pragma unroll
        for (int z = 0; z < NEe; ++z) { sc[z] = expf(sc[z] - smax); den += sc[z]; }
        float inv = 1.f / (den + 1e-20f);
        #pragma unroll
        for (int z = 0; z < NEe; ++z) aw[z][h] = sc[z] * inv;
    }
    __syncthreads();
    for (int d = tid; d < Dm; d += 256) {
        int h = d >> 6;
        float s = 0.f;
        #pragma unroll
        for (int hh = 0; hh < NEe; ++hh)
            s += hsrcB[((long)b * NEe + hh) * ldn + d] * aw[hh][h];
        nout[(long)bnn * Dm + d] = f2b(s);
    }
}

// ============================================================
extern "C" void kernel_launch(void* const* d_in, const int* in_sizes, int n_in,
                              void* d_out, int out_size, void* d_ws, size_t ws_size,
                              hipStream_t stream)
{
    const float* ctx   = (const float*)d_in[0];
    const float* att   = (const float*)d_in[1];
    const int*   mmap  = (const int*)d_in[2];
    const float* emap  = (const float*)d_in[3];
    const int*   hts   = (const int*)d_in[4];
    const float* Whb   = (const float*)d_in[5];
    const float* bhb   = (const float*)d_in[6];
    const float* Wtb   = (const float*)d_in[7];
    const float* btb   = (const float*)d_in[8];
    const float* Wbin  = (const float*)d_in[9];
    const float* bbin  = (const float*)d_in[10];
    const float* Wrel  = (const float*)d_in[11];
    const float* brel  = (const float*)d_in[12];
    const float* Wh    = (const float*)d_in[13];
    const float* bh    = (const float*)d_in[14];
    const float* Wt    = (const float*)d_in[15];
    const float* bt    = (const float*)d_in[16];
    const float* Wnode = (const float*)d_in[17];
    const float* Wni   = (const float*)d_in[18];
    const float* Wfij  = (const float*)d_in[19];
    const float* Wnj   = (const float*)d_in[20];
    const float* attp  = (const float*)d_in[21];
    const float* egatb = (const float*)d_in[22];

    float* out0 = (float*)d_out;            // bin_res [2208,2]
    float* out1 = out0 + (long)Nn * 2;      // relation_res [2208,97]

    // ---- workspace layout (~123 MB; ws ~768 MB) ----
    float* w = (float*)d_ws;
    size_t off = 0;
    auto alloc = [&](size_t nf) { float* p = w + off; off += nf; return p; };
    float* entity = alloc((size_t)Bn * NEe * Dm);
    float* curb   = alloc((size_t)Bn * Hh * NEe * Lq);     // [Tb alias]
    float* cab    = alloc((size_t)Bn * Pp * Lq);           // caH|caL (split)
    float* cib    = alloc((size_t)Nn * Dm);
    float* act1   = alloc((size_t)Nn * Dm);
    float* act2   = alloc((size_t)Nn * Dm);
    float* fijb   = alloc((size_t)Nn * Dm);
    float* foutb  = alloc((size_t)Bn * Ee * Dm);
    float* comb   = alloc((size_t)Bn * NEe * 3 * Dm);      // ni|nj|hsrc
    float* scoreb = alloc((size_t)Bn * Ee * Hh);
    float* attwb  = alloc((size_t)Bn * Ee * Hh);           // (unused, kept for layout)
    int*   maskb  = (int*)alloc(Nn);
    ushort* entbf = (ushort*)alloc((size_t)Bn * NEe * Dm / 2);  // [noutbf alias]
    ushort* cibbf = (ushort*)alloc((size_t)Nn * Dm / 2);        // [newcibf alias]
    ushort* WTe   = (ushort*)alloc((size_t)3 * Dm * Dm / 2);    // [2304][768] bf16
    ushort* WfijT = (ushort*)alloc((size_t)Dm * Dm / 2);
    ushort* WhT   = (ushort*)alloc((size_t)Dm * 2 * Dm / 2);    // [768][1536]
    ushort* WtT   = (ushort*)alloc((size_t)Dm * 2 * Dm / 2);
    ushort* WrelB = (ushort*)alloc((size_t)Dm * NPAD * 64 / 2); // [768][112][64]
    float*  Wb2   = alloc((size_t)Hh * 64 * 128);               // [h][j][i*2+o]
    ushort* entL  = (ushort*)alloc((size_t)Bn * NEe * Dm / 2);
    ushort* cibL  = (ushort*)alloc((size_t)Nn * Dm / 2);
    ushort* WhbTH = (ushort*)alloc((size_t)Dm * 2 * Dm / 2);
    ushort* WhbTL = (ushort*)alloc((size_t)Dm * 2 * Dm / 2);
    ushort* WtbTH = (ushort*)alloc((size_t)Dm * 2 * Dm / 2);
    ushort* WtbTL = (ushort*)alloc((size_t)Dm * 2 * Dm / 2);
    ushort* ctxTH = (ushort*)alloc((size_t)Bn * Dm * Lq / 2);   // [b][768][1024]
    ushort* ctxTL = (ushort*)alloc((size_t)Bn * Dm * Lq / 2);
    float*  part2 = alloc((size_t)2 * Hh * Nn * NPAD);          // j-split partials
    // aliases (lifetimes disjoint):
    float*  Tb      = curb;            // [12][2208][128] fits curb+cab
    ushort* caH     = (ushort*)cab;
    ushort* caL     = caH + (size_t)Bn * Pp * Lq;
    ushort* noutbf  = entbf;
    ushort* newcibf = cibbf;
    (void)attwb;

    // 0. weight conversions (batched; input-only deps)
    k_wT4<<<dim3(24, 24, 4), 256, 0, stream>>>(Wni, Wnj, Wnode, Wfij,
        WTe, WTe + Dm * Dm, WTe + 2 * Dm * Dm, WfijT);
    k_wT2<<<dim3(24, 48, 2), 256, 0, stream>>>(Wh, Wt, WhT, WtT, 2 * Dm, Dm);
    k_wT_split2<<<dim3(24, 48, 2), 256, 0, stream>>>(Whb, Wtb, WhbTH, WhbTL,
                                                     WtbTH, WtbTL, 2 * Dm, Dm);
    k_ctx_split<<<dim3(24, 32, 4), 256, 0, stream>>>(ctx, ctxTH, ctxTL);
    k_wrelT<<<Dm, 256, 0, stream>>>(Wrel, WrelB);
    k_wbinT<<<Hh, 256, 0, stream>>>(Wbin, Wb2);

    // 1-4. pooling + ci (pre-split 3-MFMA, ~f32 accuracy)
    k_entity<<<Bn * NEe, 256, 0, stream>>>(ctx, mmap, emap, entity, entbf, entL);
    k_cur<<<Bn * Hh * NEe, 256, 0, stream>>>(att, mmap, emap, curb);
    k_ca<<<Bn * Pp, 256, 0, stream>>>(curb, hts, caH, caL);
    k_gemm3_64<<<dim3(Dm / 64, (Pp + 63) / 64, Bn), 256, 0, stream>>>(
        caH, caL, ctxTH, ctxTL, nullptr, cib, cibbf, cibL,
        Pp, Dm, Lq, Dm, 0, (long)Pp * Lq, (long)Dm * Lq, (long)Pp * Dm);

    // 5-8. bin head (merged h/t) + T-step + reduce(+mask)
    k_gemm3_cat64<<<dim3(Dm / 64, (Nn + 63) / 64, 2), 256, 0, stream>>>(
        entbf, entL, cibbf, cibL, hts,
        WhbTH, WhbTL, WtbTH, WtbTL, bhb, btb, act1, act2);
    k_gemm_split<<<dim3(2, (Nn + 63) / 64, Hh), 256, 0, stream>>>(
        act2, Wb2, nullptr, Tb, Nn, 128, 64, Dm, 128, 128,
        64L, 64L * 128, (long)Nn * 128, 0);
    k_binred<<<Nn / 4, 256, 0, stream>>>(act1, Tb, bbin, out0, maskb);

    // 9-10. EGAT linears (bf16 MFMA) + fij
    k_gemm_bf64<<<dim3(3 * Dm / 64, 2), 256, 0, stream>>>(entbf, WTe, comb, Bn * NEe, 3 * Dm, Dm, 3 * Dm);
    k_gemm_bf64<<<dim3(Dm / 64, (Nn + 63) / 64), 256, 0, stream>>>(cibbf, WfijT, fijb, Nn, Dm, Dm, Dm);

    // 11-14. EGAT attention (fused assemble+score+newci, merged softmax+aggregate)
    k_fassemble_score<<<Bn * Ee, 256, 0, stream>>>(fijb, comb, comb + Dm, egatb, hts,
                                                   foutb, 3 * Dm, attp, maskb, scoreb,
                                                   cib, newcibf);
    k_egat_att<<<Bn * NEe, 256, 0, stream>>>(scoreb, comb + 2 * Dm, noutbf, 3 * Dm);

    // 16-17. relation head GEMMs (merged h/t, bf16 MFMA, gathered concat, tanh)
    k_gemm_bf_cat64<<<dim3(Dm / 64, (Nn + 63) / 64, 2), 256, 0, stream>>>(
        noutbf, newcibf, hts, WhT, WtT, bh, bt, act1, act2);

    // 18. relation bilinear (MFMA, j-split + XCD swizzle + W prefetch) -> out1
    k_gbl_mfma<<<432, 256, 0, stream>>>(act1, act2, WrelB, part2);
    k_rel_reduce<<<(Nn * Rr + 255) / 256, 256, 0, stream>>>(part2, brel, out1);

    (void)in_sizes; (void)n_in; (void)out_size; (void)ws_size;
}

// Round 11
// 416.515 us; speedup vs baseline: 1.3692x; 1.3692x over previous
//
#include <hip/hip_runtime.h>
#include <hip/hip_bf16.h>

// ---------------- problem constants ----------------
#define Bn   4
#define Lq   1024
#define Dm   768
#define Mm   48
#define NEe  24
#define Pp   552          // NE*(NE-1)
#define Ee   576          // P + NE (self loops)
#define Hh   12
#define BSz  64
#define Rr   97
#define Nn   2208         // B*P
#define NPAD 112          // Rr padded to 7*16
#define NEG_SLOPE 0.2f

typedef short bf16x8 __attribute__((ext_vector_type(8)));
typedef float f32x4  __attribute__((ext_vector_type(4)));

static __device__ __forceinline__ ushort f2b(float x) {
    __hip_bfloat16 h = __float2bfloat16(x);
    return *reinterpret_cast<ushort*>(&h);
}
static __device__ __forceinline__ float b2f(ushort h) {
    uint u = ((uint)h) << 16;
    return __uint_as_float(u);
}
// split f32 into hi+lo bf16 (a ~= hi + lo, residual ~2^-18 rel)
static __device__ __forceinline__ void split2(float x, ushort& h, ushort& l) {
    h = f2b(x);
    l = f2b(x - b2f(h));
}

// ============================================================
__global__ void k_entity(const float* __restrict__ ctx, const int* __restrict__ mmap,
                         const float* __restrict__ emap, float* __restrict__ entity,
                         ushort* __restrict__ entH, ushort* __restrict__ entL)
{
    int x = blockIdx.x;              // b*NE + n
    int b = x / NEe;
    int rows[8]; float wts[8]; int nnz = 0;
    for (int m = 0; m < Mm; ++m) {
        float w = emap[(long)x * Mm + m];
        if (w != 0.f && nnz < 8) { rows[nnz] = mmap[b * Mm + m]; wts[nnz] = w; ++nnz; }
    }
    const float* cbase = ctx + (long)b * Lq * Dm;
    for (int d = threadIdx.x; d < Dm; d += 256) {
        float s = 0.f;
        for (int z = 0; z < nnz; ++z) s += wts[z] * expf(cbase[(long)rows[z] * Dm + d]);
        float v = logf(s);
        entity[(long)x * Dm + d] = v;
        ushort hh, ll; split2(v, hh, ll);
        entH[(long)x * Dm + d] = hh;
        entL[(long)x * Dm + d] = ll;
    }
}

__global__ void k_cur(const float* __restrict__ att, const int* __restrict__ mmap,
                      const float* __restrict__ emap, float* __restrict__ cur)
{
    int x = blockIdx.x;
    int b = x / (Hh * NEe); int rem = x % (Hh * NEe);
    int h = rem / NEe;      int n = rem % NEe;
    float cnt = 0.f;
    int rows[8]; float wts[8]; int nnz = 0;
    for (int m = 0; m < Mm; ++m) {
        float w = emap[((long)b * NEe + n) * Mm + m];
        cnt += w;
        if (w != 0.f && nnz < 8) { rows[nnz] = mmap[b * Mm + m]; wts[nnz] = w; ++nnz; }
    }
    float inv = 1.f / (cnt + 1e-20f);
    const float* abase = att + ((long)b * Hh + h) * (long)Lq * Lq;
    float* obase = cur + (long)x * Lq;
    for (int l = threadIdx.x; l < Lq; l += 256) {
        float s = 0.f;
        for (int z = 0; z < nnz; ++z) s += wts[z] * abase[(long)rows[z] * Lq + l];
        obase[l] = s * inv;
    }
}

// ca -> split hi/lo bf16
__global__ void k_ca(const float* __restrict__ cur, const int* __restrict__ hts,
                     ushort* __restrict__ caH, ushort* __restrict__ caL)
{
    int bp = blockIdx.x; int b = bp / Pp, p = bp % Pp;
    int n0 = hts[p], n1 = hts[Pp + p];
    __shared__ float red[256];
    float vals[4]; float lsum = 0.f;
    for (int t = 0; t < 4; ++t) {
        int l = threadIdx.x + t * 256;
        float v = 0.f;
        #pragma unroll
        for (int h = 0; h < Hh; ++h) {
            v += cur[(((long)b * Hh + h) * NEe + n0) * Lq + l] *
                 cur[(((long)b * Hh + h) * NEe + n1) * Lq + l];
        }
        vals[t] = v; lsum += v;
    }
    red[threadIdx.x] = lsum; __syncthreads();
    for (int s = 128; s > 0; s >>= 1) {
        if (threadIdx.x < s) red[threadIdx.x] += red[threadIdx.x + s];
        __syncthreads();
    }
    float inv = 1.f / (red[0] + 1e-20f);
    for (int t = 0; t < 4; ++t) {
        int l = threadIdx.x + t * 256;
        float v = vals[t] * inv;
        long idx = (long)bp * Lq + l;
        ushort hh, ll; split2(v, hh, ll);
        caH[idx] = hh; caL[idx] = ll;
    }
}

// ============================================================
// split-bf16 (3-MFMA) GEMM with IN-KERNEL split (tiny T-step only)
__global__ __launch_bounds__(256)
void k_gemm_split(const float* __restrict__ A, const float* __restrict__ W,
                  const float* __restrict__ bias, float* __restrict__ C,
                  int M, int N, int K, int lda, int ldw, int ldc,
                  long sA, long sW, long sC, int act)
{
    A += (long)blockIdx.z * sA;
    W += (long)blockIdx.z * sW;
    C += (long)blockIdx.z * sC;
    __shared__ ushort Ah[64][40], Al[64][40], Bh[64][40], Bl[64][40];
    const int tid = threadIdx.x;
    const int r0 = blockIdx.y * 64, c0 = blockIdx.x * 64;
    const int w = tid >> 6, l = tid & 63, lr = l & 15, lk = l >> 4;
    const int wr = (w >> 1) * 32, wc = (w & 1) * 32;
    f32x4 acc[2][2];
    #pragma unroll
    for (int m = 0; m < 2; ++m)
        #pragma unroll
        for (int n = 0; n < 2; ++n) acc[m][n] = (f32x4){0.f, 0.f, 0.f, 0.f};

    const int ar  = tid >> 3;
    const int kq  = (tid & 7) * 4;
    const int bkk = tid >> 4;
    const int cc4 = (tid & 15) * 4;
    const float4 z4 = make_float4(0.f, 0.f, 0.f, 0.f);

    for (int k0 = 0; k0 < K; k0 += 32) {
        #pragma unroll
        for (int s = 0; s < 2; ++s) {
            int r = ar + s * 32;
            int gr = r0 + r;
            float4 v = (gr < M) ? *(const float4*)&A[(long)gr * lda + k0 + kq] : z4;
            ushort h0, l0, h1, l1;
            split2(v.x, h0, l0); split2(v.y, h1, l1);
            *(uint*)&Ah[r][kq]     = (uint)h0 | ((uint)h1 << 16);
            *(uint*)&Al[r][kq]     = (uint)l0 | ((uint)l1 << 16);
            split2(v.z, h0, l0); split2(v.w, h1, l1);
            *(uint*)&Ah[r][kq + 2] = (uint)h0 | ((uint)h1 << 16);
            *(uint*)&Al[r][kq + 2] = (uint)l0 | ((uint)l1 << 16);
        }
        #pragma unroll
        for (int s = 0; s < 2; ++s) {
            int kk = bkk + s * 16;
            float4 v = *(const float4*)&W[(long)(k0 + kk) * ldw + c0 + cc4];
            ushort hh, ll;
            split2(v.x, hh, ll); Bh[cc4 + 0][kk] = hh; Bl[cc4 + 0][kk] = ll;
            split2(v.y, hh, ll); Bh[cc4 + 1][kk] = hh; Bl[cc4 + 1][kk] = ll;
            split2(v.z, hh, ll); Bh[cc4 + 2][kk] = hh; Bl[cc4 + 2][kk] = ll;
            split2(v.w, hh, ll); Bh[cc4 + 3][kk] = hh; Bl[cc4 + 3][kk] = ll;
        }
        __syncthreads();
        bf16x8 fah[2], fal[2], fbh[2], fbl[2];
        #pragma unroll
        for (int m = 0; m < 2; ++m) {
            fah[m] = *(const bf16x8*)&Ah[wr + m * 16 + lr][lk * 8];
            fal[m] = *(const bf16x8*)&Al[wr + m * 16 + lr][lk * 8];
        }
        #pragma unroll
        for (int n = 0; n < 2; ++n) {
            fbh[n] = *(const bf16x8*)&Bh[wc + n * 16 + lr][lk * 8];
            fbl[n] = *(const bf16x8*)&Bl[wc + n * 16 + lr][lk * 8];
        }
        #pragma unroll
        for (int m = 0; m < 2; ++m)
            #pragma unroll
            for (int n = 0; n < 2; ++n) {
                acc[m][n] = __builtin_amdgcn_mfma_f32_16x16x32_bf16(fal[m], fbh[n], acc[m][n], 0, 0, 0);
                acc[m][n] = __builtin_amdgcn_mfma_f32_16x16x32_bf16(fah[m], fbl[n], acc[m][n], 0, 0, 0);
                acc[m][n] = __builtin_amdgcn_mfma_f32_16x16x32_bf16(fah[m], fbh[n], acc[m][n], 0, 0, 0);
            }
        __syncthreads();
    }
    #pragma unroll
    for (int m = 0; m < 2; ++m) {
        #pragma unroll
        for (int q = 0; q < 4; ++q) {
            int gr = r0 + wr + m * 16 + lk * 4 + q;
            if (gr >= M) continue;
            #pragma unroll
            for (int n = 0; n < 2; ++n) {
                int gc = c0 + wc + n * 16 + lr;
                float v = acc[m][n][q] + (bias ? bias[gc] : 0.f);
                if (act) v = tanhf(v);
                C[(long)gr * ldc + gc] = v;
            }
        }
    }
}

// ============================================================
// 64^2-tile pre-split 3-MFMA GEMM (batched): C = act(A @ Bt^T + bias)
__global__ __launch_bounds__(256)
void k_gemm3_64(const ushort* __restrict__ AH, const ushort* __restrict__ AL,
                const ushort* __restrict__ BH, const ushort* __restrict__ BL,
                const float* __restrict__ bias, float* __restrict__ C,
                ushort* __restrict__ Ch, ushort* __restrict__ Cl,
                int M, int N, int K, int ldc, int act,
                long sA, long sB, long sC)
{
    AH += blockIdx.z * sA; AL += blockIdx.z * sA;
    BH += blockIdx.z * sB; BL += blockIdx.z * sB;
    C  += blockIdx.z * sC;
    ushort* ChB = Ch ? Ch + blockIdx.z * sC : (ushort*)nullptr;
    ushort* ClB = Cl ? Cl + blockIdx.z * sC : (ushort*)nullptr;
    __shared__ ushort AsH[64][40], AsL[64][40], BsH[64][40], BsL[64][40];
    const int tid = threadIdx.x;
    const int r0 = blockIdx.y * 64, c0 = blockIdx.x * 64;
    const int w = tid >> 6, l = tid & 63, lr = l & 15, lk = l >> 4;
    const int wr = (w >> 1) * 32, wc = (w & 1) * 32;
    f32x4 acc[2][2];
    #pragma unroll
    for (int m = 0; m < 2; ++m)
        #pragma unroll
        for (int n = 0; n < 2; ++n) acc[m][n] = (f32x4){0.f, 0.f, 0.f, 0.f};

    const int srow = tid >> 2, scb = (tid & 1) * 16;
    const bool doB = (tid >> 1) & 1;
    const bool ok = doB ? (c0 + srow < N) : (r0 + srow < M);
    const long g = doB ? (long)(c0 + srow) : (long)(r0 + srow);
    const ushort* pH = (doB ? BH : AH) + (ok ? g : 0) * (long)K;
    const ushort* pL = (doB ? BL : AL) + (ok ? g : 0) * (long)K;
    ushort (*dH)[40] = doB ? BsH : AsH;
    ushort (*dL)[40] = doB ? BsL : AsL;
    const uint4 z4 = make_uint4(0, 0, 0, 0);
    for (int k0 = 0; k0 < K; k0 += 32) {
        int kc = k0 + scb;
        *(uint4*)&dH[srow][scb]     = ok ? *(const uint4*)&pH[kc]     : z4;
        *(uint4*)&dH[srow][scb + 8] = ok ? *(const uint4*)&pH[kc + 8] : z4;
        *(uint4*)&dL[srow][scb]     = ok ? *(const uint4*)&pL[kc]     : z4;
        *(uint4*)&dL[srow][scb + 8] = ok ? *(const uint4*)&pL[kc + 8] : z4;
        __syncthreads();
        bf16x8 ah[2], al_[2], bh[2], bl_[2];
        #pragma unroll
        for (int m = 0; m < 2; ++m) {
            ah[m]  = *(const bf16x8*)&AsH[wr + m * 16 + lr][lk * 8];
            al_[m] = *(const bf16x8*)&AsL[wr + m * 16 + lr][lk * 8];
        }
        #pragma unroll
        for (int n = 0; n < 2; ++n) {
            bh[n]  = *(const bf16x8*)&BsH[wc + n * 16 + lr][lk * 8];
            bl_[n] = *(const bf16x8*)&BsL[wc + n * 16 + lr][lk * 8];
        }
        #pragma unroll
        for (int m = 0; m < 2; ++m)
            #pragma unroll
            for (int n = 0; n < 2; ++n) {
                acc[m][n] = __builtin_amdgcn_mfma_f32_16x16x32_bf16(al_[m], bh[n], acc[m][n], 0, 0, 0);
                acc[m][n] = __builtin_amdgcn_mfma_f32_16x16x32_bf16(ah[m], bl_[n], acc[m][n], 0, 0, 0);
                acc[m][n] = __builtin_amdgcn_mfma_f32_16x16x32_bf16(ah[m], bh[n], acc[m][n], 0, 0, 0);
            }
        __syncthreads();
    }
    #pragma unroll
    for (int m = 0; m < 2; ++m) {
        #pragma unroll
        for (int q = 0; q < 4; ++q) {
            int gr = r0 + wr + m * 16 + lk * 4 + q;
            if (gr >= M) continue;
            #pragma unroll
            for (int n = 0; n < 2; ++n) {
                int gc = c0 + wc + n * 16 + lr;
                float v = acc[m][n][q] + (bias ? bias[gc] : 0.f);
                if (act) v = tanhf(v);
                long oi = (long)gr * ldc + gc;
                C[oi] = v;
                if (ChB) { ushort hh, ll; split2(v, hh, ll); ChB[oi] = hh; ClB[oi] = ll; }
            }
        }
    }
}

// 64^2-tile pre-split 3-MFMA GEMM, gathered concat, tanh; z picks (sel,W,bias,C)
__global__ __launch_bounds__(256)
void k_gemm3_cat64(const ushort* __restrict__ ndH, const ushort* __restrict__ ndL,
                   const ushort* __restrict__ ftH, const ushort* __restrict__ ftL,
                   const int* __restrict__ hts,
                   const ushort* __restrict__ BH0, const ushort* __restrict__ BL0,
                   const ushort* __restrict__ BH1, const ushort* __restrict__ BL1,
                   const float* __restrict__ bias0, const float* __restrict__ bias1,
                   float* __restrict__ C0, float* __restrict__ C1)
{
    const int zz = blockIdx.z;
    const int* sel = hts + (zz ? Pp : 0);
    const ushort* BH = zz ? BH1 : BH0;
    const ushort* BL = zz ? BL1 : BL0;
    const float* bias = zz ? bias1 : bias0;
    float* C = zz ? C1 : C0;
    __shared__ ushort AsH[64][40], AsL[64][40], BsH[64][40], BsL[64][40];
    const int tid = threadIdx.x;
    const int r0 = blockIdx.y * 64, c0 = blockIdx.x * 64;
    const int w = tid >> 6, l = tid & 63, lr = l & 15, lk = l >> 4;
    const int wr = (w >> 1) * 32, wc = (w & 1) * 32;
    f32x4 acc[2][2];
    #pragma unroll
    for (int m = 0; m < 2; ++m)
        #pragma unroll
        for (int n = 0; n < 2; ++n) acc[m][n] = (f32x4){0.f, 0.f, 0.f, 0.f};

    const int srow = tid >> 2, scb = (tid & 1) * 16;
    const bool doB = (tid >> 1) & 1;
    const ushort *pH0, *pL0, *pH1, *pL1;
    bool ok;
    if (doB) {
        long gc = c0 + srow;            // N=768 exact
        ok = true;
        pH0 = BH + gc * (long)(2 * Dm); pL0 = BL + gc * (long)(2 * Dm);
        pH1 = pH0; pL1 = pL0;
    } else {
        int gra = r0 + srow;
        ok = gra < Nn;
        int grc = ok ? gra : Nn - 1;
        int b = grc / Pp, p = grc % Pp;
        pH0 = ndH + ((long)b * NEe + sel[p]) * Dm;
        pL0 = ndL + ((long)b * NEe + sel[p]) * Dm;
        pH1 = ftH + (long)grc * Dm - Dm;
        pL1 = ftL + (long)grc * Dm - Dm;
    }
    ushort (*dH)[40] = doB ? BsH : AsH;
    ushort (*dL)[40] = doB ? BsL : AsL;
    const uint4 z4 = make_uint4(0, 0, 0, 0);
    for (int k0 = 0; k0 < 2 * Dm; k0 += 32) {
        const ushort* sH = ((k0 < Dm) ? pH0 : pH1) + k0 + scb;
        const ushort* sL = ((k0 < Dm) ? pL0 : pL1) + k0 + scb;
        *(uint4*)&dH[srow][scb]     = ok ? *(const uint4*)sH       : z4;
        *(uint4*)&dH[srow][scb + 8] = ok ? *(const uint4*)(sH + 8) : z4;
        *(uint4*)&dL[srow][scb]     = ok ? *(const uint4*)sL       : z4;
        *(uint4*)&dL[srow][scb + 8] = ok ? *(const uint4*)(sL + 8) : z4;
        __syncthreads();
        bf16x8 ah[2], al_[2], bh[2], bl_[2];
        #pragma unroll
        for (int m = 0; m < 2; ++m) {
            ah[m]  = *(const bf16x8*)&AsH[wr + m * 16 + lr][lk * 8];
            al_[m] = *(const bf16x8*)&AsL[wr + m * 16 + lr][lk * 8];
        }
        #pragma unroll
        for (int n = 0; n < 2; ++n) {
            bh[n]  = *(const bf16x8*)&BsH[wc + n * 16 + lr][lk * 8];
            bl_[n] = *(const bf16x8*)&BsL[wc + n * 16 + lr][lk * 8];
        }
        #pragma unroll
        for (int m = 0; m < 2; ++m)
            #pragma unroll
            for (int n = 0; n < 2; ++n) {
                acc[m][n] = __builtin_amdgcn_mfma_f32_16x16x32_bf16(al_[m], bh[n], acc[m][n], 0, 0, 0);
                acc[m][n] = __builtin_amdgcn_mfma_f32_16x16x32_bf16(ah[m], bl_[n], acc[m][n], 0, 0, 0);
                acc[m][n] = __builtin_amdgcn_mfma_f32_16x16x32_bf16(ah[m], bh[n], acc[m][n], 0, 0, 0);
            }
        __syncthreads();
    }
    #pragma unroll
    for (int m = 0; m < 2; ++m) {
        #pragma unroll
        for (int q = 0; q < 4; ++q) {
            int gr = r0 + wr + m * 16 + lk * 4 + q;
            if (gr >= Nn) continue;
            #pragma unroll
            for (int n = 0; n < 2; ++n) {
                int gc = c0 + wc + n * 16 + lr;
                C[(long)gr * Dm + gc] = tanhf(acc[m][n][q] + bias[gc]);
            }
        }
    }
}

// 64^2-tile plain bf16 GEMM: C = A @ Bt^T
__global__ __launch_bounds__(256)
void k_gemm_bf64(const ushort* __restrict__ A, const ushort* __restrict__ Bt,
                 float* __restrict__ C, int M, int N, int K, int ldc)
{
    __shared__ ushort As[64][40], Bs[64][40];
    const int tid = threadIdx.x;
    const int r0 = blockIdx.y * 64, c0 = blockIdx.x * 64;
    const int w = tid >> 6, l = tid & 63, lr = l & 15, lk = l >> 4;
    const int wr = (w >> 1) * 32, wc = (w & 1) * 32;
    f32x4 acc[2][2];
    #pragma unroll
    for (int m = 0; m < 2; ++m)
        #pragma unroll
        for (int n = 0; n < 2; ++n) acc[m][n] = (f32x4){0.f, 0.f, 0.f, 0.f};

    const int srow = tid >> 2, scb = (tid & 1) * 16;
    const bool doB = (tid >> 1) & 1;
    const bool ok = doB ? (c0 + srow < N) : (r0 + srow < M);
    const long g = doB ? (long)(c0 + srow) : (long)(r0 + srow);
    const ushort* p = (doB ? Bt : A) + (ok ? g : 0) * (long)K;
    ushort (*d)[40] = doB ? Bs : As;
    const uint4 z4 = make_uint4(0, 0, 0, 0);
    for (int k0 = 0; k0 < K; k0 += 32) {
        int kc = k0 + scb;
        *(uint4*)&d[srow][scb]     = ok ? *(const uint4*)&p[kc]     : z4;
        *(uint4*)&d[srow][scb + 8] = ok ? *(const uint4*)&p[kc + 8] : z4;
        __syncthreads();
        bf16x8 af[2], bf_[2];
        #pragma unroll
        for (int m = 0; m < 2; ++m) af[m]  = *(const bf16x8*)&As[wr + m * 16 + lr][lk * 8];
        #pragma unroll
        for (int n = 0; n < 2; ++n) bf_[n] = *(const bf16x8*)&Bs[wc + n * 16 + lr][lk * 8];
        #pragma unroll
        for (int m = 0; m < 2; ++m)
            #pragma unroll
            for (int n = 0; n < 2; ++n)
                acc[m][n] = __builtin_amdgcn_mfma_f32_16x16x32_bf16(af[m], bf_[n], acc[m][n], 0, 0, 0);
        __syncthreads();
    }
    #pragma unroll
    for (int m = 0; m < 2; ++m) {
        #pragma unroll
        for (int q = 0; q < 4; ++q) {
            int gr = r0 + wr + m * 16 + lk * 4 + q;
            if (gr >= M) continue;
            #pragma unroll
            for (int n = 0; n < 2; ++n) {
                int gc = c0 + wc + n * 16 + lr;
                C[(long)gr * ldc + gc] = acc[m][n][q];
            }
        }
    }
}

// 64^2-tile plain bf16 GEMM, gathered concat, tanh; z picks (sel,W,bias,C)
__global__ __launch_bounds__(256)
void k_gemm_bf_cat64(const ushort* __restrict__ nodes, const ushort* __restrict__ feat,
                     const int* __restrict__ hts,
                     const ushort* __restrict__ Bt0, const ushort* __restrict__ Bt1,
                     const float* __restrict__ bias0, const float* __restrict__ bias1,
                     float* __restrict__ C0, float* __restrict__ C1)
{
    const int zz = blockIdx.z;
    const int* sel = hts + (zz ? Pp : 0);
    const ushort* Bt = zz ? Bt1 : Bt0;
    const float* bias = zz ? bias1 : bias0;
    float* C = zz ? C1 : C0;
    __shared__ ushort As[64][40], Bs[64][40];
    const int tid = threadIdx.x;
    const int r0 = blockIdx.y * 64, c0 = blockIdx.x * 64;
    const int w = tid >> 6, l = tid & 63, lr = l & 15, lk = l >> 4;
    const int wr = (w >> 1) * 32, wc = (w & 1) * 32;
    f32x4 acc[2][2];
    #pragma unroll
    for (int m = 0; m < 2; ++m)
        #pragma unroll
        for (int n = 0; n < 2; ++n) acc[m][n] = (f32x4){0.f, 0.f, 0.f, 0.f};

    const int srow = tid >> 2, scb = (tid & 1) * 16;
    const bool doB = (tid >> 1) & 1;
    const ushort *p0, *p1;
    bool ok;
    if (doB) {
        long gc = c0 + srow;
        ok = true;
        p0 = Bt + gc * (long)(2 * Dm);
        p1 = p0;
    } else {
        int gra = r0 + srow;
        ok = gra < Nn;
        int grc = ok ? gra : Nn - 1;
        int b = grc / Pp, p = grc % Pp;
        p0 = nodes + ((long)b * NEe + sel[p]) * Dm;
        p1 = feat + (long)grc * Dm - Dm;
    }
    ushort (*d)[40] = doB ? Bs : As;
    const uint4 z4 = make_uint4(0, 0, 0, 0);
    for (int k0 = 0; k0 < 2 * Dm; k0 += 32) {
        const ushort* s = ((k0 < Dm) ? p0 : p1) + k0 + scb;
        *(uint4*)&d[srow][scb]     = ok ? *(const uint4*)s       : z4;
        *(uint4*)&d[srow][scb + 8] = ok ? *(const uint4*)(s + 8) : z4;
        __syncthreads();
        bf16x8 af[2], bf_[2];
        #pragma unroll
        for (int m = 0; m < 2; ++m) af[m]  = *(const bf16x8*)&As[wr + m * 16 + lr][lk * 8];
        #pragma unroll
        for (int n = 0; n < 2; ++n) bf_[n] = *(const bf16x8*)&Bs[wc + n * 16 + lr][lk * 8];
        #pragma unroll
        for (int m = 0; m < 2; ++m)
            #pragma unroll
            for (int n = 0; n < 2; ++n)
                acc[m][n] = __builtin_amdgcn_mfma_f32_16x16x32_bf16(af[m], bf_[n], acc[m][n], 0, 0, 0);
        __syncthreads();
    }
    #pragma unroll
    for (int m = 0; m < 2; ++m) {
        #pragma unroll
        for (int q = 0; q < 4; ++q) {
            int gr = r0 + wr + m * 16 + lk * 4 + q;
            if (gr >= Nn) continue;
            #pragma unroll
            for (int n = 0; n < 2; ++n) {
                int gc = c0 + wc + n * 16 + lr;
                C[(long)gr * Dm + gc] = tanhf(acc[m][n][q] + bias[gc]);
            }
        }
    }
}

// Wbin [(h*64+i)*64+j][2] -> Wb2[h][j][i*2+o] f32
__global__ void k_wbinT(const float* __restrict__ W, float* __restrict__ out)
{
    int h = blockIdx.x;              // 0..11
    for (int idx = threadIdx.x; idx < 64 * 128; idx += 256) {
        int j = idx >> 7, io = idx & 127;
        int i = io >> 1, o = io & 1;
        out[(long)h * 64 * 128 + idx] = W[(((long)h * 64 + i) * 64 + j) * 2 + o];
    }
}

// out0[n][o] = bbin[o] + sum_{h,i} act1[n][h*64+i] * T[h][n][i*2+o]; also mask
__global__ void k_binred(const float* __restrict__ act1, const float* __restrict__ T,
                         const float* __restrict__ bias, float* __restrict__ out0,
                         int* __restrict__ maskb)
{
    int w = threadIdx.x >> 6, l = threadIdx.x & 63;
    int n = blockIdx.x * 4 + w;
    if (n >= Nn) return;
    float a0 = 0.f, a1 = 0.f;
    #pragma unroll
    for (int h = 0; h < Hh; ++h) {
        float a = act1[(long)n * Dm + h * 64 + l];
        const float* t = T + ((long)(h * Nn + n)) * 128 + l * 2;
        a0 += a * t[0];
        a1 += a * t[1];
    }
    #pragma unroll
    for (int off = 32; off > 0; off >>= 1) {
        a0 += __shfl_down(a0, off);
        a1 += __shfl_down(a1, off);
    }
    if (l == 0) {
        float v0 = a0 + bias[0], v1 = a1 + bias[1];
        out0[n * 2 + 0] = v0;
        out0[n * 2 + 1] = v1;
        maskb[n] = v1 > v0 ? 1 : 0;
    }
}

// ---------- batched weight transpose kernels ----------
__global__ void k_wT4(const float* __restrict__ i0, const float* __restrict__ i1,
                      const float* __restrict__ i2, const float* __restrict__ i3,
                      ushort* __restrict__ o0, ushort* __restrict__ o1,
                      ushort* __restrict__ o2, ushort* __restrict__ o3)
{
    const float* in; ushort* out;
    switch (blockIdx.z) {
        case 0: in = i0; out = o0; break;
        case 1: in = i1; out = o1; break;
        case 2: in = i2; out = o2; break;
        default: in = i3; out = o3; break;
    }
    __shared__ float t[32][33];
    int k0 = blockIdx.y * 32, n0 = blockIdx.x * 32;
    int tx = threadIdx.x & 31, ty = threadIdx.x >> 5;
    #pragma unroll
    for (int s = 0; s < 4; ++s)
        t[ty + s * 8][tx] = in[(long)(k0 + ty + s * 8) * Dm + n0 + tx];
    __syncthreads();
    #pragma unroll
    for (int s = 0; s < 4; ++s)
        out[(long)(n0 + ty + s * 8) * Dm + k0 + tx] = f2b(t[tx][ty + s * 8]);
}

__global__ void k_wT2(const float* __restrict__ i0, const float* __restrict__ i1,
                      ushort* __restrict__ o0, ushort* __restrict__ o1, int K, int N)
{
    const float* in = blockIdx.z ? i1 : i0;
    ushort* out = blockIdx.z ? o1 : o0;
    __shared__ float t[32][33];
    int k0 = blockIdx.y * 32, n0 = blockIdx.x * 32;
    int tx = threadIdx.x & 31, ty = threadIdx.x >> 5;
    #pragma unroll
    for (int s = 0; s < 4; ++s)
        t[ty + s * 8][tx] = in[(long)(k0 + ty + s * 8) * N + n0 + tx];
    __syncthreads();
    #pragma unroll
    for (int s = 0; s < 4; ++s)
        out[(long)(n0 + ty + s * 8) * K + k0 + tx] = f2b(t[tx][ty + s * 8]);
}

__global__ void k_wT_split2(const float* __restrict__ i0, const float* __restrict__ i1,
                            ushort* __restrict__ oH0, ushort* __restrict__ oL0,
                            ushort* __restrict__ oH1, ushort* __restrict__ oL1,
                            int K, int N)
{
    const float* in = blockIdx.z ? i1 : i0;
    ushort* outH = blockIdx.z ? oH1 : oH0;
    ushort* outL = blockIdx.z ? oL1 : oL0;
    __shared__ float t[32][33];
    int k0 = blockIdx.y * 32, n0 = blockIdx.x * 32;
    int tx = threadIdx.x & 31, ty = threadIdx.x >> 5;
    #pragma unroll
    for (int s = 0; s < 4; ++s)
        t[ty + s * 8][tx] = in[(long)(k0 + ty + s * 8) * N + n0 + tx];
    __syncthreads();
    #pragma unroll
    for (int s = 0; s < 4; ++s) {
        float v = t[tx][ty + s * 8];
        ushort hh, ll; split2(v, hh, ll);
        long oi = (long)(n0 + ty + s * 8) * K + k0 + tx;
        outH[oi] = hh;
        outL[oi] = ll;
    }
}

__global__ void k_ctx_split(const float* __restrict__ ctx, ushort* __restrict__ outH,
                            ushort* __restrict__ outL)
{
    const float* in = ctx + (long)blockIdx.z * Lq * Dm;
    ushort* oH = outH + (long)blockIdx.z * Dm * Lq;
    ushort* oL = outL + (long)blockIdx.z * Dm * Lq;
    __shared__ float t[32][33];
    int k0 = blockIdx.y * 32, n0 = blockIdx.x * 32;   // k over Lq, n over Dm
    int tx = threadIdx.x & 31, ty = threadIdx.x >> 5;
    #pragma unroll
    for (int s = 0; s < 4; ++s)
        t[ty + s * 8][tx] = in[(long)(k0 + ty + s * 8) * Dm + n0 + tx];
    __syncthreads();
    #pragma unroll
    for (int s = 0; s < 4; ++s) {
        float v = t[tx][ty + s * 8];
        ushort hh, ll; split2(v, hh, ll);
        long oi = (long)(n0 + ty + s * 8) * Lq + k0 + tx;
        oH[oi] = hh;
        oL[oi] = ll;
    }
}

// Wrel [(h*64+i)*64+j][97] -> WrelB[(hi*112 + o)*64 + j] bf16 (o>=97 -> 0)
__global__ void k_wrelT(const float* __restrict__ W, ushort* __restrict__ out)
{
    int hi = blockIdx.x;            // 0..767
    for (int idx = threadIdx.x; idx < NPAD * 64; idx += 256) {
        int o = idx >> 6, j = idx & 63;
        float v = (o < Rr) ? W[((long)hi * 64 + j) * Rr + o] : 0.f;
        out[(long)hi * NPAD * 64 + idx] = f2b(v);
    }
}

// ---------- MFMA blockwise bilinear: j-split + XCD swizzle + NAMED double-buffer ----------
// (rule #20: no runtime-indexed fragment arrays; 2x-unrolled i-loop with bA/bB)
__global__ __launch_bounds__(256)
void k_gbl_mfma(const float* __restrict__ Aact, const float* __restrict__ Cact,
                const ushort* __restrict__ Wt, float* __restrict__ part)
{
    const int bid = blockIdx.x;      // 0..431
    const int xcd = bid & 7, sb = bid >> 3;   // sb 0..53
    int h, t;
    if (sb < 36) { h = xcd;             t = sb; }
    else         { h = 8 + (xcd >> 1);  t = (sb - 36) + 18 * (xcd & 1); }
    const int rb = t >> 1, jh = t & 1;
    const int r0 = rb * 128;
    const int j0 = jh * 32;
    __shared__ float a_s[128][68];
    const int tid = threadIdx.x;
    {   // stage a-block [128][64]
        int row = tid >> 1, cb = (tid & 1) * 32;
        long gr = r0 + row;
        if (gr < Nn) {
            const float* ap = Aact + gr * Dm + h * BSz + cb;
            #pragma unroll
            for (int q = 0; q < 32; q += 4)
                *(float4*)&a_s[row][cb + q] = *(const float4*)&ap[q];
        } else {
            #pragma unroll
            for (int q = 0; q < 32; ++q) a_s[row][cb + q] = 0.f;
        }
    }
    __syncthreads();
    const int w = tid >> 6, l = tid & 63, lr = l & 15, lk = l >> 4;
    const int wr = w * 32;
    f32x4 acc[2][7];
    #pragma unroll
    for (int m = 0; m < 2; ++m)
        #pragma unroll
        for (int n = 0; n < 7; ++n) acc[m][n] = (f32x4){0.f, 0.f, 0.f, 0.f};

    const ushort* wbase = Wt + (long)h * 64 * NPAD * 64 + j0 + lk * 8;   // [i][o][j]
    float cc[2][8];
    #pragma unroll
    for (int m = 0; m < 2; ++m) {
        int crow = r0 + wr + m * 16 + lr;
        if (crow >= Nn) crow = Nn - 1;   // a=0 there anyway
        const float* cp = Cact + (long)crow * Dm + h * BSz + j0 + lk * 8;
        float4 clo = *(const float4*)cp;
        float4 chi = *(const float4*)(cp + 4);
        cc[m][0] = clo.x; cc[m][1] = clo.y; cc[m][2] = clo.z; cc[m][3] = clo.w;
        cc[m][4] = chi.x; cc[m][5] = chi.y; cc[m][6] = chi.z; cc[m][7] = chi.w;
    }
    // named double buffers, all indices compile-time constant
    bf16x8 bA[7], bB[7];
    #pragma unroll
    for (int n = 0; n < 7; ++n)
        bA[n] = *(const bf16x8*)(wbase + (long)(n * 16 + lr) * 64);
    for (int i = 0; i < 64; i += 2) {
        {   // prefetch i+1 -> bB
            const ushort* wp = wbase + (long)(i + 1) * NPAD * 64;
            #pragma unroll
            for (int n = 0; n < 7; ++n)
                bB[n] = *(const bf16x8*)(wp + (long)(n * 16 + lr) * 64);
        }
        #pragma unroll
        for (int m = 0; m < 2; ++m) {   // compute i with bA
            float av = a_s[wr + m * 16 + lr][i];
            bf16x8 af;
            #pragma unroll
            for (int q = 0; q < 8; ++q)
                af[q] = (short)f2b(av * cc[m][q]);
            #pragma unroll
            for (int n = 0; n < 7; ++n)
                acc[m][n] = __builtin_amdgcn_mfma_f32_16x16x32_bf16(af, bA[n], acc[m][n], 0, 0, 0);
        }
        if (i + 2 < 64) {   // prefetch i+2 -> bA
            const ushort* wp = wbase + (long)(i + 2) * NPAD * 64;
            #pragma unroll
            for (int n = 0; n < 7; ++n)
                bA[n] = *(const bf16x8*)(wp + (long)(n * 16 + lr) * 64);
        }
        #pragma unroll
        for (int m = 0; m < 2; ++m) {   // compute i+1 with bB
            float av = a_s[wr + m * 16 + lr][i + 1];
            bf16x8 af;
            #pragma unroll
            for (int q = 0; q < 8; ++q)
                af[q] = (short)f2b(av * cc[m][q]);
            #pragma unroll
            for (int n = 0; n < 7; ++n)
                acc[m][n] = __builtin_amdgcn_mfma_f32_16x16x32_bf16(af, bB[n], acc[m][n], 0, 0, 0);
        }
    }
    float* pdst = part + ((long)(h * 2 + jh) * Nn) * NPAD;
    #pragma unroll
    for (int m = 0; m < 2; ++m) {
        #pragma unroll
        for (int q = 0; q < 4; ++q) {
            int gr = r0 + wr + m * 16 + lk * 4 + q;
            if (gr >= Nn) continue;
            #pragma unroll
            for (int n = 0; n < 7; ++n) {
                int o = n * 16 + lr;
                pdst[(long)gr * NPAD + o] = acc[m][n][q];
            }
        }
    }
}

__global__ void k_rel_reduce(const float* __restrict__ part, const float* __restrict__ bias,
                             float* __restrict__ out)
{
    int idx = blockIdx.x * 256 + threadIdx.x;
    if (idx >= Nn * Rr) return;
    int n = idx / Rr, o = idx % Rr;
    float s = bias[o];
    #pragma unroll
    for (int h = 0; h < 2 * Hh; ++h) s += part[((long)h * Nn + n) * NPAD + o];
    out[idx] = s;
}

// f_out assembly + fused edge score + fused new_ci (bf16)
__global__ void k_fassemble_score(const float* __restrict__ fij, const float* __restrict__ ni,
                                  const float* __restrict__ nj, const float* __restrict__ eb,
                                  const int* __restrict__ hts, float* __restrict__ fout, int ldn,
                                  const float* __restrict__ attp, const int* __restrict__ mask,
                                  float* __restrict__ score,
                                  const float* __restrict__ ci, ushort* __restrict__ newci)
{
    int be = blockIdx.x; int b = be / Ee, e = be % Ee;
    int sn, dn; const float* fe = nullptr;
    if (e < Pp) { sn = hts[e]; dn = hts[Pp + e]; fe = fij + ((long)b * Pp + e) * Dm; }
    else        { sn = dn = e - Pp; }
    const float* nib = ni + ((long)b * NEe + sn) * ldn;
    const float* njb = nj + ((long)b * NEe + dn) * ldn;
    float* ob = fout + (long)be * Dm;
    const bool okm = (e >= Pp) || (mask[b * Pp + e] != 0);
    const long nrow = (long)b * Pp + e;       // valid when e < Pp
    __shared__ float sd[Dm];
    for (int d = threadIdx.x; d < Dm; d += 256) {
        float v = (fe ? fe[d] : 0.f) + nib[d] + njb[d] + eb[d];
        ob[d] = v;
        float lr = v >= 0.f ? v : NEG_SLOPE * v;
        sd[d] = lr * attp[d];
        if (e < Pp)
            newci[nrow * Dm + d] = f2b(okm ? v : ci[nrow * Dm + d]);
    }
    __syncthreads();
    const int wv = threadIdx.x >> 6, ln = threadIdx.x & 63;
    for (int h = wv; h < Hh; h += 4) {
        float s = sd[h * 64 + ln];
        #pragma unroll
        for (int off = 32; off > 0; off >>= 1) s += __shfl_down(s, off);
        if (ln == 0) score[(long)be * Hh + h] = okm ? s : -1e30f;
    }
}

// merged edge-softmax + node aggregation; block = (b,n); attw in LDS
__global__ void k_egat_att(const float* __restrict__ score, const float* __restrict__ hsrcB,
                           ushort* __restrict__ nout, int ldn)
{
    int bnn = blockIdx.x; int b = bnn / NEe, n = bnn % NEe;
    __shared__ float aw[NEe][Hh + 1];
    int tid = threadIdx.x;
    if (tid < Hh) {
        int h = tid;
        float sc[NEe];
        float smax = -3e38f;
        #pragma unroll
        for (int hh = 0; hh < NEe; ++hh) {
            int e;
            if (hh == n) e = Pp + n;
            else         e = hh * (NEe - 1) + (n - (n > hh ? 1 : 0));
            float v = score[((long)b * Ee + e) * Hh + h];
            sc[hh] = v;
            smax = fmaxf(smax, v);
        }
        float den = 0.f;
        #pragma unroll
        for (int z = 0; z < NEe; ++z) { sc[z] = expf(sc[z] - smax); den += sc[z]; }
        float inv = 1.f / (den + 1e-20f);
        #pragma unroll
        for (int z = 0; z < NEe; ++z) aw[z][h] = sc[z] * inv;
    }
    __syncthreads();
    for (int d = tid; d < Dm; d += 256) {
        int h = d >> 6;
        float s = 0.f;
        #pragma unroll
        for (int hh = 0; hh < NEe; ++hh)
            s += hsrcB[((long)b * NEe + hh) * ldn + d] * aw[hh][h];
        nout[(long)bnn * Dm + d] = f2b(s);
    }
}

// ============================================================
extern "C" void kernel_launch(void* const* d_in, const int* in_sizes, int n_in,
                              void* d_out, int out_size, void* d_ws, size_t ws_size,
                              hipStream_t stream)
{
    const float* ctx   = (const float*)d_in[0];
    const float* att   = (const float*)d_in[1];
    const int*   mmap  = (const int*)d_in[2];
    const float* emap  = (const float*)d_in[3];
    const int*   hts   = (const int*)d_in[4];
    const float* Whb   = (const float*)d_in[5];
    const float* bhb   = (const float*)d_in[6];
    const float* Wtb   = (const float*)d_in[7];
    const float* btb   = (const float*)d_in[8];
    const float* Wbin  = (const float*)d_in[9];
    const float* bbin  = (const float*)d_in[10];
    const float* Wrel  = (const float*)d_in[11];
    const float* brel  = (const float*)d_in[12];
    const float* Wh    = (const float*)d_in[13];
    const float* bh    = (const float*)d_in[14];
    const float* Wt    = (const float*)d_in[15];
    const float* bt    = (const float*)d_in[16];
    const float* Wnode = (const float*)d_in[17];
    const float* Wni   = (const float*)d_in[18];
    const float* Wfij  = (const float*)d_in[19];
    const float* Wnj   = (const float*)d_in[20];
    const float* attp  = (const float*)d_in[21];
    const float* egatb = (const float*)d_in[22];

    float* out0 = (float*)d_out;            // bin_res [2208,2]
    float* out1 = out0 + (long)Nn * 2;      // relation_res [2208,97]

    // ---- workspace layout (~123 MB; ws ~768 MB) ----
    float* w = (float*)d_ws;
    size_t off = 0;
    auto alloc = [&](size_t nf) { float* p = w + off; off += nf; return p; };
    float* entity = alloc((size_t)Bn * NEe * Dm);
    float* curb   = alloc((size_t)Bn * Hh * NEe * Lq);     // [Tb alias]
    float* cab    = alloc((size_t)Bn * Pp * Lq);           // caH|caL (split)
    float* cib    = alloc((size_t)Nn * Dm);
    float* act1   = alloc((size_t)Nn * Dm);
    float* act2   = alloc((size_t)Nn * Dm);
    float* fijb   = alloc((size_t)Nn * Dm);
    float* foutb  = alloc((size_t)Bn * Ee * Dm);
    float* comb   = alloc((size_t)Bn * NEe * 3 * Dm);      // ni|nj|hsrc
    float* scoreb = alloc((size_t)Bn * Ee * Hh);
    float* attwb  = alloc((size_t)Bn * Ee * Hh);           // (unused, kept for layout)
    int*   maskb  = (int*)alloc(Nn);
    ushort* entbf = (ushort*)alloc((size_t)Bn * NEe * Dm / 2);  // [noutbf alias]
    ushort* cibbf = (ushort*)alloc((size_t)Nn * Dm / 2);        // [newcibf alias]
    ushort* WTe   = (ushort*)alloc((size_t)3 * Dm * Dm / 2);    // [2304][768] bf16
    ushort* WfijT = (ushort*)alloc((size_t)Dm * Dm / 2);
    ushort* WhT   = (ushort*)alloc((size_t)Dm * 2 * Dm / 2);    // [768][1536]
    ushort* WtT   = (ushort*)alloc((size_t)Dm * 2 * Dm / 2);
    ushort* WrelB = (ushort*)alloc((size_t)Dm * NPAD * 64 / 2); // [768][112][64]
    float*  Wb2   = alloc((size_t)Hh * 64 * 128);               // [h][j][i*2+o]
    ushort* entL  = (ushort*)alloc((size_t)Bn * NEe * Dm / 2);
    ushort* cibL  = (ushort*)alloc((size_t)Nn * Dm / 2);
    ushort* WhbTH = (ushort*)alloc((size_t)Dm * 2 * Dm / 2);
    ushort* WhbTL = (ushort*)alloc((size_t)Dm * 2 * Dm / 2);
    ushort* WtbTH = (ushort*)alloc((size_t)Dm * 2 * Dm / 2);
    ushort* WtbTL = (ushort*)alloc((size_t)Dm * 2 * Dm / 2);
    ushort* ctxTH = (ushort*)alloc((size_t)Bn * Dm * Lq / 2);   // [b][768][1024]
    ushort* ctxTL = (ushort*)alloc((size_t)Bn * Dm * Lq / 2);
    float*  part2 = alloc((size_t)2 * Hh * Nn * NPAD);          // j-split partials
    // aliases (lifetimes disjoint):
    float*  Tb      = curb;            // [12][2208][128] fits curb+cab
    ushort* caH     = (ushort*)cab;
    ushort* caL     = caH + (size_t)Bn * Pp * Lq;
    ushort* noutbf  = entbf;
    ushort* newcibf = cibbf;
    (void)attwb;

    // 0. weight conversions (batched; input-only deps)
    k_wT4<<<dim3(24, 24, 4), 256, 0, stream>>>(Wni, Wnj, Wnode, Wfij,
        WTe, WTe + Dm * Dm, WTe + 2 * Dm * Dm, WfijT);
    k_wT2<<<dim3(24, 48, 2), 256, 0, stream>>>(Wh, Wt, WhT, WtT, 2 * Dm, Dm);
    k_wT_split2<<<dim3(24, 48, 2), 256, 0, stream>>>(Whb, Wtb, WhbTH, WhbTL,
                                                     WtbTH, WtbTL, 2 * Dm, Dm);
    k_ctx_split<<<dim3(24, 32, 4), 256, 0, stream>>>(ctx, ctxTH, ctxTL);
    k_wrelT<<<Dm, 256, 0, stream>>>(Wrel, WrelB);
    k_wbinT<<<Hh, 256, 0, stream>>>(Wbin, Wb2);

    // 1-4. pooling + ci (pre-split 3-MFMA, ~f32 accuracy)
    k_entity<<<Bn * NEe, 256, 0, stream>>>(ctx, mmap, emap, entity, entbf, entL);
    k_cur<<<Bn * Hh * NEe, 256, 0, stream>>>(att, mmap, emap, curb);
    k_ca<<<Bn * Pp, 256, 0, stream>>>(curb, hts, caH, caL);
    k_gemm3_64<<<dim3(Dm / 64, (Pp + 63) / 64, Bn), 256, 0, stream>>>(
        caH, caL, ctxTH, ctxTL, nullptr, cib, cibbf, cibL,
        Pp, Dm, Lq, Dm, 0, (long)Pp * Lq, (long)Dm * Lq, (long)Pp * Dm);

    // 5-8. bin head (merged h/t) + T-step + reduce(+mask)
    k_gemm3_cat64<<<dim3(Dm / 64, (Nn + 63) / 64, 2), 256, 0, stream>>>(
        entbf, entL, cibbf, cibL, hts,
        WhbTH, WhbTL, WtbTH, WtbTL, bhb, btb, act1, act2);
    k_gemm_split<<<dim3(2, (Nn + 63) / 64, Hh), 256, 0, stream>>>(
        act2, Wb2, nullptr, Tb, Nn, 128, 64, Dm, 128, 128,
        64L, 64L * 128, (long)Nn * 128, 0);
    k_binred<<<Nn / 4, 256, 0, stream>>>(act1, Tb, bbin, out0, maskb);

    // 9-10. EGAT linears (bf16 MFMA) + fij
    k_gemm_bf64<<<dim3(3 * Dm / 64, 2), 256, 0, stream>>>(entbf, WTe, comb, Bn * NEe, 3 * Dm, Dm, 3 * Dm);
    k_gemm_bf64<<<dim3(Dm / 64, (Nn + 63) / 64), 256, 0, stream>>>(cibbf, WfijT, fijb, Nn, Dm, Dm, Dm);

    // 11-14. EGAT attention (fused assemble+score+newci, merged softmax+aggregate)
    k_fassemble_score<<<Bn * Ee, 256, 0, stream>>>(fijb, comb, comb + Dm, egatb, hts,
                                                   foutb, 3 * Dm, attp, maskb, scoreb,
                                                   cib, newcibf);
    k_egat_att<<<Bn * NEe, 256, 0, stream>>>(scoreb, comb + 2 * Dm, noutbf, 3 * Dm);

    // 16-17. relation head GEMMs (merged h/t, bf16 MFMA, gathered concat, tanh)
    k_gemm_bf_cat64<<<dim3(Dm / 64, (Nn + 63) / 64, 2), 256, 0, stream>>>(
        noutbf, newcibf, hts, WhT, WtT, bh, bt, act1, act2);

    // 18. relation bilinear (MFMA, j-split + XCD swizzle + named dbuf) -> out1
    k_gbl_mfma<<<432, 256, 0, stream>>>(act1, act2, WrelB, part2);
    k_rel_reduce<<<(Nn * Rr + 255) / 256, 256, 0, stream>>>(part2, brel, out1);

    (void)in_sizes; (void)n_in; (void)out_size; (void)ws_size;
}